// Round 16
// baseline (23104.611 us; speedup 1.0000x reference)
//
#include <hip/hip_runtime.h>
#include <hip/hip_bf16.h>
#include <stdint.h>
#include <stddef.h>

using bf16_t = __hip_bfloat16;
typedef __attribute__((ext_vector_type(8))) short short8;
typedef __attribute__((ext_vector_type(4))) float f32x4;

__device__ __forceinline__ void gload_lds16(void* lds, const void* g) {
  __builtin_amdgcn_global_load_lds(
      (const __attribute__((address_space(1))) unsigned int*)g,
      (__attribute__((address_space(3))) unsigned int*)lds,
      16, 0, 0);
}

// ---------------------------------------------------------------------------
// Deep-pipelined GEMM: C[m][n] = sum_k A[m][k]*B[n][k].
// BM=BN=128, BK=64. 512 threads = 8 waves (2x4), wave tile 64x32.
// Grid = (M/128)*(N/128) = 256 (or 128/64) -> 1 block/CU, 2 waves/SIMD.
// 3-buffer LDS ring (96 KB), prefetch depth 2, counted vmcnt (T4):
//   [wait vmcnt(8): retire tile tt, keep tt+1/tt+2 in flight]
//   [barrier] [compute tt: ds_read/MFMA interleaved, setprio (T5)]
//   [barrier] [stage tt+3 -> buf tt%3 (freed by barrier 2)]
// Loads are issued ~2 iterations (~2500 cy) before their vmcnt wait ->
// latency fully hidden without cross-block TLP (m201 regime, 1 block/CU).
// LDS 16B-chunk XOR swizzle (slot s^(row&7)) via pre-swizzled global source.
// XCD-bijective 1-D grid swizzle (nwg % 8 == 0).
// Algebraic scheme (r14/r15): W13 = W1@W3, fp32 yw1 recursion, Stot sum.
// MODEs: 0 gmid, 1 gvst, 2 gyw1, 3 gw13, 4 gfin, 5 gs1v (see r15).
// ---------------------------------------------------------------------------
template<int MODE>
__device__ __forceinline__ void gemm_core(
    const bf16_t* __restrict__ A, const bf16_t* __restrict__ B,
    const float* __restrict__ bias,
    bf16_t* __restrict__ obf,
    bf16_t* __restrict__ aux,          // M0: hsum (bf16 RMW)
    bf16_t* __restrict__ vout,         // M1: v store
    float* __restrict__ wacc,          // M1 rd / M2 wr / M5 rmw : yw1 fp32
    float* __restrict__ yf_out,        // M2: Stot zero  M4: out  M5: Stot rmw
    const float* __restrict__ y_in,    // M4: x   M5: b1 vector
    const bf16_t* __restrict__ p0, const bf16_t* __restrict__ p1,
    const bf16_t* __restrict__ p2, const bf16_t* __restrict__ p3,
    float c0, float c1, float c2, float c3, float ccur, int hinit,
    int M, int N, int K, int lgx)
{
  __shared__ __align__(16) bf16_t As[3][128 * 64];
  __shared__ __align__(16) bf16_t Bs[3][128 * 64];

  const int t    = threadIdx.x;
  const int lane = t & 63;
  const int wid  = t >> 6;          // 0..7
  const int wm   = wid >> 2;        // 0..1  (64-row band)
  const int wn   = wid & 3;         // 0..3  (32-col band)

  const int nwg = gridDim.x, bid = blockIdx.x;
  const int swz = (bid & 7) * (nwg >> 3) + (bid >> 3);
  const int gxm = (1 << lgx) - 1;
  const int bx  = swz & gxm;
  const int by  = swz >> lgx;
  const int bn0 = bx * 128, bm0 = by * 128;

  const bf16_t* Ag = A + (size_t)bm0 * K;
  const bf16_t* Bg = B + (size_t)bn0 * K;

  f32x4 acc[4][2] = {};

  // stage tile kt into buffer b: 1024 chunks each for A and B, 512 threads
  // -> 2+2 gload_lds per thread. chunk(row,s) holds slot s^(row&7).
  auto stage = [&](int b, int kt) {
    const int k0 = kt * 64;
#pragma unroll
    for (int r = 0; r < 2; ++r) {
      int ch  = t + r * 512;
      int row = ch >> 3, s = ch & 7;
      int sl  = s ^ (row & 7);
      gload_lds16(&As[b][ch * 8], Ag + (size_t)row * K + k0 + sl * 8);
    }
#pragma unroll
    for (int r = 0; r < 2; ++r) {
      int ch  = t + r * 512;
      int row = ch >> 3, s = ch & 7;
      int sl  = s ^ (row & 7);
      gload_lds16(&Bs[b][ch * 8], Bg + (size_t)row * K + k0 + sl * 8);
    }
  };

  const int nt = K >> 6;                    // 8 or 16 (>= 3)
  stage(0, 0); stage(1, 1); stage(2, 2);    // depth-2 prologue: 12 loads

  const int ro = lane & 15;
  const int ks = lane >> 4;

  int c = 0;                                // buffer of tile tt
  for (int tt = 0; tt < nt; ++tt) {
    const int rem = nt - 1 - tt;
    if (rem >= 2)      asm volatile("s_waitcnt vmcnt(8)" ::: "memory");
    else if (rem == 1) asm volatile("s_waitcnt vmcnt(4)" ::: "memory");
    else               asm volatile("s_waitcnt vmcnt(0)" ::: "memory");
    __builtin_amdgcn_s_barrier();           // tile tt visible to all waves
    asm volatile("" ::: "memory");

#pragma unroll
    for (int kk = 0; kk < 2; ++kk) {
      short8 af[4], bfr[2];
      const int slot = kk * 4 + ks;
#pragma unroll
      for (int mi = 0; mi < 4; ++mi) {
        int row = wm * 64 + mi * 16 + ro;
        int ch  = row * 8 + (slot ^ (row & 7));
        af[mi]  = *(const short8*)&As[c][ch * 8];
      }
#pragma unroll
      for (int ni = 0; ni < 2; ++ni) {
        int row = wn * 32 + ni * 16 + ro;
        int ch  = row * 8 + (slot ^ (row & 7));
        bfr[ni] = *(const short8*)&Bs[c][ch * 8];
      }
      __builtin_amdgcn_s_setprio(1);
#pragma unroll
      for (int mi = 0; mi < 4; ++mi)
#pragma unroll
        for (int ni = 0; ni < 2; ++ni)
          acc[mi][ni] = __builtin_amdgcn_mfma_f32_16x16x32_bf16(
              af[mi], bfr[ni], acc[mi][ni], 0, 0, 0);
      __builtin_amdgcn_s_setprio(0);
    }

    asm volatile("" ::: "memory");
    __builtin_amdgcn_s_barrier();           // all waves done reading buf c
    asm volatile("" ::: "memory");
    if (tt + 3 < nt) stage(c, tt + 3);      // buf c freed; refill with tt+3
    if (++c == 3) c = 0;
  }

  // ---- epilogue -----------------------------------------------------------
  const int rb = bm0 + wm * 64;
  const int cb = bn0 + wn * 32;
#pragma unroll
  for (int mi = 0; mi < 4; ++mi) {
#pragma unroll
    for (int ni = 0; ni < 2; ++ni) {
      const int col = cb + ni * 16 + ro;
      const float bv = bias ? bias[col] : 0.f;
#pragma unroll
      for (int r = 0; r < 4; ++r) {
        const int row = rb + mi * 16 + (lane >> 4) * 4 + r;
        const size_t idx = (size_t)row * N + col;
        const float a = acc[mi][ni][r];
        if (MODE == 0) {
          float v = fmaxf(a + bv, 0.f);
          obf[idx] = __float2bfloat16(v);
          if (aux) {
            float hs = ccur * v + (hinit ? 0.f : __bfloat162float(aux[idx]));
            aux[idx] = __float2bfloat16(hs);
          }
        } else if (MODE == 1) {
          vout[idx] = __float2bfloat16(a);
          float u = wacc[idx] + ccur * a + bv;
          if (p0) u += c0 * __bfloat162float(p0[idx]);
          if (p1) u += c1 * __bfloat162float(p1[idx]);
          if (p2) u += c2 * __bfloat162float(p2[idx]);
          if (p3) u += c3 * __bfloat162float(p3[idx]);
          obf[idx] = __float2bfloat16(fmaxf(u, 0.f));
        } else if (MODE == 2) {
          wacc[idx]   = a;
          yf_out[idx] = 0.f;
          obf[idx]    = __float2bfloat16(fmaxf(a + bv, 0.f));
        } else if (MODE == 3) {
          obf[idx] = __float2bfloat16(a);
        } else if (MODE == 4) {
          yf_out[idx] = y_in[idx] + a + ccur * bv;
        } else {  // MODE 5
          float u = wacc[idx] + a + ccur * bv;      // bv = c13, ccur = h
          wacc[idx] = u;
          yf_out[idx] += __bfloat162float(p0[idx]); // Stot += hsum_{n-1}
          obf[idx] = __float2bfloat16(fmaxf(u + y_in[col], 0.f)); // + b1
        }
      }
    }
  }
}

#define GARGS                                                               \
    const bf16_t* A, const bf16_t* B, const float* bias, bf16_t* obf,       \
    bf16_t* aux, bf16_t* vout, float* wacc, float* yf_out,                  \
    const float* y_in,                                                      \
    const bf16_t* p0, const bf16_t* p1, const bf16_t* p2, const bf16_t* p3, \
    float c0, float c1, float c2, float c3, float ccur, int hinit,          \
    int M, int N, int K, int lgx
#define GPASS A,B,bias,obf,aux,vout,wacc,yf_out,y_in,p0,p1,p2,p3,c0,c1,c2,c3,ccur,hinit,M,N,K,lgx

extern "C" __global__ void __launch_bounds__(512, 1) gmid(GARGS) { gemm_core<0>(GPASS); }
extern "C" __global__ void __launch_bounds__(512, 1) gvst(GARGS) { gemm_core<1>(GPASS); }
extern "C" __global__ void __launch_bounds__(512, 1) gyw1(GARGS) { gemm_core<2>(GPASS); }
extern "C" __global__ void __launch_bounds__(512, 1) gw13(GARGS) { gemm_core<3>(GPASS); }
extern "C" __global__ void __launch_bounds__(512, 1) gfin(GARGS) { gemm_core<4>(GPASS); }
extern "C" __global__ void __launch_bounds__(512, 1) gs1v(GARGS) { gemm_core<5>(GPASS); }

// ---------------------------------------------------------------------------
extern "C" __global__ void init_all(
    const float* __restrict__ x,
    const float* __restrict__ W1, const float* __restrict__ W2,
    const float* __restrict__ W3,
    const float* __restrict__ b1, const float* __restrict__ b3,
    bf16_t* __restrict__ W1b, bf16_t* __restrict__ W2b,
    bf16_t* __restrict__ W3b, bf16_t* __restrict__ W3Tb,
    bf16_t* __restrict__ yb,
    float* __restrict__ c13f,
    float* __restrict__ bS2, float* __restrict__ bS3, float* __restrict__ bS4,
    float* __restrict__ bS5, float* __restrict__ bS6,
    float s2, float s3, float s4, float s5, float s6)
{
  const int gt = blockIdx.x * blockDim.x + threadIdx.x;
  const int gs = gridDim.x * blockDim.x;
  auto cvt4 = [&](const float* in, bf16_t* outp, int n) {
    for (int i = gt * 4; i < n; i += gs * 4) {
      float4 v = *(const float4*)(in + i);
      bf16_t o[4] = {__float2bfloat16(v.x), __float2bfloat16(v.y),
                     __float2bfloat16(v.z), __float2bfloat16(v.w)};
      *(uint64_t*)(outp + i) = *(uint64_t*)o;
    }
  };
  cvt4(W1, W1b, 1024 * 512);
  cvt4(W2, W2b, 1024 * 1024);
  cvt4(W3, W3b, 512 * 1024);
  cvt4(x, (bf16_t*)yb, 4096 * 512);
  for (int i = gt; i < 512 * 1024; i += gs) {      // W3T[j][d] = W3[d][j]
    int d = i >> 10, j = i & 1023;
    W3Tb[(size_t)j * 512 + d] = __float2bfloat16(W3[i]);
  }
  if (gt < 1024) {
    float c13 = 0.f;
    const float* wr = W1 + (size_t)gt * 512;
    for (int d = 0; d < 512; ++d) c13 += b3[d] * wr[d];
    const float bb = b1[gt];
    c13f[gt] = c13;
    bS2[gt] = bb + s2 * c13;
    bS3[gt] = bb + s3 * c13;
    bS4[gt] = bb + s4 * c13;
    bS5[gt] = bb + s5 * c13;
    bS6[gt] = bb + s6 * c13;
  }
}

// Stotb = bf16(Stot + hsum_63)
extern "C" __global__ void ewfin(const float* __restrict__ Stot,
                                 const bf16_t* __restrict__ hsum,
                                 bf16_t* __restrict__ Stotb, int n)
{
  const int gt = blockIdx.x * blockDim.x + threadIdx.x;
  const int gs = gridDim.x * blockDim.x;
  for (int i = gt * 4; i < n; i += gs * 4) {
    float4 s = *(const float4*)(Stot + i);
    uint64_t hv = *(const uint64_t*)(hsum + i);
    const bf16_t* hp = (const bf16_t*)&hv;
    bf16_t o[4];
    o[0] = __float2bfloat16(s.x + __bfloat162float(hp[0]));
    o[1] = __float2bfloat16(s.y + __bfloat162float(hp[1]));
    o[2] = __float2bfloat16(s.z + __bfloat162float(hp[2]));
    o[3] = __float2bfloat16(s.w + __bfloat162float(hp[3]));
    *(uint64_t*)(Stotb + i) = *(uint64_t*)o;
  }
}

// ---------------------------------------------------------------------------
extern "C" void kernel_launch(void* const* d_in, const int* in_sizes, int n_in,
                              void* d_out, int out_size, void* d_ws, size_t ws_size,
                              hipStream_t stream)
{
  const float* x  = (const float*)d_in[0];
  const float* W1 = (const float*)d_in[1];
  const float* b1 = (const float*)d_in[2];
  const float* W2 = (const float*)d_in[3];
  const float* b2 = (const float*)d_in[4];
  const float* W3 = (const float*)d_in[5];
  const float* b3 = (const float*)d_in[6];

  constexpr int BATCH = 4096, DATA = 512, HID = 1024;

  char* ws = (char*)d_ws;
  size_t off = 0;
  auto alloc = [&](size_t bytes) -> void* {
    off = (off + 255) & ~(size_t)255;
    void* p = ws + off;
    off += bytes;
    return p;
  };
  const size_t nyd = (size_t)BATCH * DATA;
  const size_t nh  = (size_t)BATCH * HID;

  bf16_t* yb   = (bf16_t*)alloc(nyd * 2);
  bf16_t* h1b  = (bf16_t*)alloc(nh * 2);
  bf16_t* h2b  = (bf16_t*)alloc(nh * 2);
  float*  yw1f = (float*)alloc(nh * 4);
  float*  Stot = (float*)alloc(nh * 4);
  bf16_t* Stotb= (bf16_t*)alloc(nh * 2);
  bf16_t* hsumb= (bf16_t*)alloc(nh * 2);
  bf16_t* v1   = (bf16_t*)alloc(nh * 2);
  bf16_t* v2   = (bf16_t*)alloc(nh * 2);
  bf16_t* v3   = (bf16_t*)alloc(nh * 2);
  bf16_t* v4   = (bf16_t*)alloc(nh * 2);
  bf16_t* v5   = (bf16_t*)alloc(nh * 2);
  bf16_t* W1b  = (bf16_t*)alloc((size_t)HID * DATA * 2);
  bf16_t* W2b  = (bf16_t*)alloc((size_t)HID * HID * 2);
  bf16_t* W3b  = (bf16_t*)alloc((size_t)DATA * HID * 2);
  bf16_t* W3Tb = (bf16_t*)alloc((size_t)HID * DATA * 2);
  bf16_t* W13b = (bf16_t*)alloc((size_t)HID * HID * 2);
  float*  c13f = (float*)alloc(HID * 4);
  float*  bS2  = (float*)alloc(HID * 4);
  float*  bS3  = (float*)alloc(HID * 4);
  float*  bS4  = (float*)alloc(HID * 4);
  float*  bS5  = (float*)alloc(HID * 4);
  float*  bS6  = (float*)alloc(HID * 4);

  const double hh = 1.0 / 64.0;
  const float hA21 = (float)(hh * (1.0/5.0));
  const float hA31 = (float)(hh * (3.0/40.0)),    hA32 = (float)(hh * (9.0/40.0));
  const float hA41 = (float)(hh * (44.0/45.0)),   hA42 = (float)(hh * (-56.0/15.0)),
              hA43 = (float)(hh * (32.0/9.0));
  const float hA51 = (float)(hh * (19372.0/6561.0)),  hA52 = (float)(hh * (-25360.0/2187.0)),
              hA53 = (float)(hh * (64448.0/6561.0)),  hA54 = (float)(hh * (-212.0/729.0));
  const float hA61 = (float)(hh * (9017.0/3168.0)),   hA62 = (float)(hh * (-355.0/33.0)),
              hA63 = (float)(hh * (46732.0/5247.0)),  hA64 = (float)(hh * (49.0/176.0)),
              hA65 = (float)(hh * (-5103.0/18656.0));
  const float hB1 = (float)(hh * (35.0/384.0)),   hB3 = (float)(hh * (500.0/1113.0)),
              hB4 = (float)(hh * (125.0/192.0)),  hB5 = (float)(hh * (-2187.0/6784.0)),
              hB6 = (float)(hh * (11.0/84.0));
  const float s2 = hA21, s3 = hA31 + hA32, s4 = hA41 + hA42 + hA43,
              s5 = hA51 + hA52 + hA53 + hA54,
              s6 = hA61 + hA62 + hA63 + hA64 + hA65;

  init_all<<<2048, 256, 0, stream>>>(x, W1, W2, W3, b1, b3,
                                     W1b, W2b, W3b, W3Tb, yb,
                                     c13f, bS2, bS3, bS4, bS5, bS6,
                                     s2, s3, s4, s5, s6);

  const dim3 blk(512);
  const int gridN = (HID / 128) * (BATCH / 128);   // 8*32 = 256, lgx=3
  const int gridY = (DATA / 128) * (BATCH / 128);  // 4*32 = 128, lgx=2
  const int gridW = (HID / 128) * (HID / 128);     // 8*8  = 64,  lgx=3

  // W13 = W1 @ W3
  gw13<<<gridW, blk, 0, stream>>>(
      W1b, W3Tb, nullptr, W13b, nullptr, nullptr, nullptr, nullptr, nullptr,
      nullptr, nullptr, nullptr, nullptr, 0.f, 0.f, 0.f, 0.f, 0.f, 0,
      HID, HID, DATA, 3);

  auto G2 = [&](bf16_t* hs, float coef, int hinit) {
    gmid<<<gridN, blk, 0, stream>>>(
        h1b, W2b, b2, h2b, hs, nullptr, nullptr, nullptr, nullptr,
        nullptr, nullptr, nullptr, nullptr,
        0.f, 0.f, 0.f, 0.f, coef, hinit, BATCH, HID, HID, 3);
  };
  auto V = [&](bf16_t* vo, const float* bS, float ccur,
               const bf16_t* q0, float cc0, const bf16_t* q1, float cc1,
               const bf16_t* q2, float cc2, const bf16_t* q3, float cc3) {
    gvst<<<gridN, blk, 0, stream>>>(
        h2b, W13b, bS, h1b, nullptr, vo, yw1f, nullptr, nullptr,
        q0, q1, q2, q3, cc0, cc1, cc2, cc3, ccur, 0, BATCH, HID, HID, 3);
  };

  for (int step = 0; step < 64; ++step) {
    if (step == 0) {
      gyw1<<<gridN, blk, 0, stream>>>(
          yb, W1b, b1, h1b, nullptr, nullptr, yw1f, Stot, nullptr,
          nullptr, nullptr, nullptr, nullptr,
          0.f, 0.f, 0.f, 0.f, 0.f, 0, BATCH, HID, DATA, 3);
    } else {
      gs1v<<<gridN, blk, 0, stream>>>(
          hsumb, W13b, c13f, h1b, nullptr, nullptr, yw1f, Stot, b1,
          hsumb, nullptr, nullptr, nullptr,
          0.f, 0.f, 0.f, 0.f, (float)hh, 0, BATCH, HID, HID, 3);
    }
    G2(hsumb, hB1, 1);
    V(v1, bS2, hA21, nullptr,0,nullptr,0,nullptr,0,nullptr,0);
    G2(nullptr, 0.f, 0);
    V(v2, bS3, hA32, v1,hA31, nullptr,0,nullptr,0,nullptr,0);
    G2(hsumb, hB3, 0);
    V(v3, bS4, hA43, v1,hA41, v2,hA42, nullptr,0,nullptr,0);
    G2(hsumb, hB4, 0);
    V(v4, bS5, hA54, v1,hA51, v2,hA52, v3,hA53, nullptr,0);
    G2(hsumb, hB5, 0);
    V(v5, bS6, hA65, v1,hA61, v2,hA62, v3,hA63, v4,hA64);
    G2(hsumb, hB6, 0);
  }

  ewfin<<<1024, 256, 0, stream>>>(Stot, hsumb, Stotb, (int)nh);
  gfin<<<gridY, blk, 0, stream>>>(
      Stotb, W3b, b3, nullptr, nullptr, nullptr, nullptr, (float*)d_out, x,
      nullptr, nullptr, nullptr, nullptr,
      0.f, 0.f, 0.f, 0.f, 1.0f, 0, BATCH, DATA, HID, 2);
}

// Round 17
// 21931.303 us; speedup vs baseline: 1.0535x; 1.0535x over previous
//
#include <hip/hip_runtime.h>
#include <hip/hip_bf16.h>
#include <stdint.h>
#include <stddef.h>

using bf16_t = __hip_bfloat16;
typedef __attribute__((ext_vector_type(8))) short short8;
typedef __attribute__((ext_vector_type(4))) float f32x4;

__device__ __forceinline__ void gload_lds16(void* lds, const void* g) {
  __builtin_amdgcn_global_load_lds(
      (const __attribute__((address_space(1))) unsigned int*)g,
      (__attribute__((address_space(3))) unsigned int*)lds,
      16, 0, 0);
}

// ---------------------------------------------------------------------------
// GEMM C[m][n] = sum_k A[m][k]*B[n][k].  BM=128 x BN=64, BK=64 (44 FLOP per
// staged byte vs 32 at 64x64 -- the L2-staging-BW fix), 4 waves (2x2), wave
// tile 64x32 (acc 4x2).  A: LDS 2-buffer ring w/ 16B-chunk XOR swizzle via
// pre-swizzled global source.  B: packed-fragment weights (r11-validated
// format) DIRECT global->VGPR, register ping-pong one tile ahead:
//   frag(ntile,kt,kk) at elem ((ntile*(K/64)+kt)*2+kk)*512 + lane*8
// Per phase: [vmcnt(4): retire A(tt), keep B(tt) in flight] [barrier]
// [stageA(tt+1); loadB(tt+1)] [compute tt].  Grid 512 -> 2 blocks/CU.
// XCD-bijective swizzle (nwg%8==0), M-striped per XCD (L2-local chain).
// MODEs (r15 algebraic scheme: W13=W1@W3, fp32 yw1 recursion, Stot):
//  0 gmid, 1 gvst, 2 gyw1, 3 gw13, 4 gfin, 5 gs1v.
// ---------------------------------------------------------------------------
template<int MODE>
__device__ __forceinline__ void gemm_core(
    const bf16_t* __restrict__ A, const bf16_t* __restrict__ Bp,
    const float* __restrict__ bias,
    bf16_t* __restrict__ obf,
    bf16_t* __restrict__ aux,
    bf16_t* __restrict__ vout,
    float* __restrict__ wacc,
    float* __restrict__ yf_out,
    const float* __restrict__ y_in,
    const bf16_t* __restrict__ p0, const bf16_t* __restrict__ p1,
    const bf16_t* __restrict__ p2, const bf16_t* __restrict__ p3,
    float c0, float c1, float c2, float c3, float ccur, int hinit,
    int M, int N, int K, int lgx)
{
  __shared__ __align__(16) bf16_t As[2][128 * 64];

  const int t    = threadIdx.x;
  const int lane = t & 63;
  const int wid  = t >> 6;
  const int wm   = wid >> 1;        // 0..1: 64-row band
  const int wn   = wid & 1;         // 0..1: 32-col band

  const int nwg = gridDim.x, bid = blockIdx.x;
  const int swz = (bid & 7) * (nwg >> 3) + (bid >> 3);
  const int gxm = (1 << lgx) - 1;
  const int bx  = swz & gxm;
  const int by  = swz >> lgx;
  const int bn0 = bx * 64, bm0 = by * 128;

  const bf16_t* Ag = A + (size_t)bm0 * K;
  const int ntk = K >> 6;                       // 8 or 16 (even)
  const bf16_t* Bw = Bp + ((size_t)(bx * 4 + wn * 2) * ntk * 2) * 512
                        + (size_t)lane * 8;

  // A tile 128x64 = 1024 chunks of 16B; 4 gloads/thread
  auto stageA = [&](int b, int kt) {
    const int k0 = kt * 64;
#pragma unroll
    for (int r = 0; r < 4; ++r) {
      int ch  = t + r * 256;
      int row = ch >> 3, s = ch & 7;
      int sl  = s ^ (row & 7);
      gload_lds16(&As[b][ch * 8], Ag + (size_t)row * K + k0 + sl * 8);
    }
  };
  auto loadB = [&](short8* dst, int kt) {
#pragma unroll
    for (int ni = 0; ni < 2; ++ni)
#pragma unroll
      for (int kk = 0; kk < 2; ++kk)
        dst[ni * 2 + kk] = *(const short8*)
            (Bw + ((size_t)ni * ntk * 2 + kt * 2 + kk) * 512);
  };

  f32x4 acc[4][2] = {};
  const int ro = lane & 15;
  const int ks = lane >> 4;

  auto compute = [&](const bf16_t* lds, const short8* bfr) {
#pragma unroll
    for (int kk = 0; kk < 2; ++kk) {
      short8 af[4];
      const int slot = kk * 4 + ks;
#pragma unroll
      for (int mi = 0; mi < 4; ++mi) {
        int row = wm * 64 + mi * 16 + ro;
        int ch  = row * 8 + (slot ^ (row & 7));
        af[mi]  = *(const short8*)&lds[ch * 8];
      }
      __builtin_amdgcn_s_setprio(1);
#pragma unroll
      for (int mi = 0; mi < 4; ++mi)
#pragma unroll
        for (int ni = 0; ni < 2; ++ni)
          acc[mi][ni] = __builtin_amdgcn_mfma_f32_16x16x32_bf16(
              af[mi], bfr[ni * 2 + kk], acc[mi][ni], 0, 0, 0);
      __builtin_amdgcn_s_setprio(0);
    }
  };

  short8 b0[4], b1[4];
  stageA(0, 0);
  loadB(b0, 0);

  for (int tt = 0; tt < ntk; tt += 2) {
    // phase 0: tile tt (A-buf 0, regs b0)
    asm volatile("s_waitcnt vmcnt(4)" ::: "memory");   // retire A(tt)
    __builtin_amdgcn_s_barrier();
    asm volatile("" ::: "memory");
    stageA(1, tt + 1);                 // ntk even -> tt+1 < ntk
    loadB(b1, tt + 1);
    compute(As[0], b0);

    // phase 1: tile tt+1 (A-buf 1, regs b1)
    asm volatile("s_waitcnt vmcnt(4)" ::: "memory");   // retire A(tt+1)
    __builtin_amdgcn_s_barrier();
    asm volatile("" ::: "memory");
    if (tt + 2 < ntk) {
      stageA(0, tt + 2);
      loadB(b0, tt + 2);
    }
    compute(As[1], b1);
  }

  // ---- epilogue -----------------------------------------------------------
  const int rb = bm0 + wm * 64;
  const int cb = bn0 + wn * 32;
#pragma unroll
  for (int mi = 0; mi < 4; ++mi) {
#pragma unroll
    for (int ni = 0; ni < 2; ++ni) {
      const int col = cb + ni * 16 + ro;
      const float bv = bias ? bias[col] : 0.f;
#pragma unroll
      for (int r = 0; r < 4; ++r) {
        const int row = rb + mi * 16 + (lane >> 4) * 4 + r;
        const size_t idx = (size_t)row * N + col;
        const float a = acc[mi][ni][r];
        if (MODE == 0) {
          float v = fmaxf(a + bv, 0.f);
          obf[idx] = __float2bfloat16(v);
          if (aux) {
            float hs = ccur * v + (hinit ? 0.f : __bfloat162float(aux[idx]));
            aux[idx] = __float2bfloat16(hs);
          }
        } else if (MODE == 1) {
          vout[idx] = __float2bfloat16(a);
          float u = wacc[idx] + ccur * a + bv;
          if (p0) u += c0 * __bfloat162float(p0[idx]);
          if (p1) u += c1 * __bfloat162float(p1[idx]);
          if (p2) u += c2 * __bfloat162float(p2[idx]);
          if (p3) u += c3 * __bfloat162float(p3[idx]);
          obf[idx] = __float2bfloat16(fmaxf(u, 0.f));
        } else if (MODE == 2) {
          wacc[idx]   = a;
          yf_out[idx] = 0.f;
          obf[idx]    = __float2bfloat16(fmaxf(a + bv, 0.f));
        } else if (MODE == 3) {
          obf[idx] = __float2bfloat16(a);
        } else if (MODE == 4) {
          yf_out[idx] = y_in[idx] + a + ccur * bv;
        } else {  // MODE 5
          float u = wacc[idx] + a + ccur * bv;      // bv=c13, ccur=h
          wacc[idx] = u;
          yf_out[idx] += __bfloat162float(p0[idx]); // Stot += hsum
          obf[idx] = __float2bfloat16(fmaxf(u + y_in[col], 0.f)); // +b1
        }
      }
    }
  }
}

#define GARGS                                                               \
    const bf16_t* A, const bf16_t* B, const float* bias, bf16_t* obf,       \
    bf16_t* aux, bf16_t* vout, float* wacc, float* yf_out,                  \
    const float* y_in,                                                      \
    const bf16_t* p0, const bf16_t* p1, const bf16_t* p2, const bf16_t* p3, \
    float c0, float c1, float c2, float c3, float ccur, int hinit,          \
    int M, int N, int K, int lgx
#define GPASS A,B,bias,obf,aux,vout,wacc,yf_out,y_in,p0,p1,p2,p3,c0,c1,c2,c3,ccur,hinit,M,N,K,lgx

extern "C" __global__ void __launch_bounds__(256, 2) gmid(GARGS) { gemm_core<0>(GPASS); }
extern "C" __global__ void __launch_bounds__(256, 2) gvst(GARGS) { gemm_core<1>(GPASS); }
extern "C" __global__ void __launch_bounds__(256, 2) gyw1(GARGS) { gemm_core<2>(GPASS); }
extern "C" __global__ void __launch_bounds__(256, 2) gw13(GARGS) { gemm_core<3>(GPASS); }
extern "C" __global__ void __launch_bounds__(256, 2) gfin(GARGS) { gemm_core<4>(GPASS); }
extern "C" __global__ void __launch_bounds__(256, 2) gs1v(GARGS) { gemm_core<5>(GPASS); }

// ---------------------------------------------------------------------------
// packing: frag chunk c -> lane=c&63; kk=(c>>6)&1; kt=(c>>7)%ktn;
// ntile=c/(ktn*128); src row ntile*16+(lane&15), col kt*64+kk*32+(lane>>4)*8
// ---------------------------------------------------------------------------
__device__ __forceinline__ void pack_w(const float* __restrict__ W,
                                       bf16_t* __restrict__ Wp,
                                       int N, int K, int gt, int gs)
{
  const int nchunk = (N * K) / 8;
  const int ktn = K >> 6;
  for (int c = gt; c < nchunk; c += gs) {
    int lane = c & 63, kk = (c >> 6) & 1, kt = (c >> 7) % ktn;
    int ntile = c / (ktn * 128);
    const float* src = W + (size_t)(ntile * 16 + (lane & 15)) * K
                         + kt * 64 + kk * 32 + (lane >> 4) * 8;
    bf16_t o[8];
#pragma unroll
    for (int j = 0; j < 8; ++j) o[j] = __float2bfloat16(src[j]);
    *(short8*)(Wp + (size_t)c * 8) = *(short8*)o;
  }
}

// pack W3^T (logical B[j][d] = W3[d][j], rows j<1024, K=512)
__device__ __forceinline__ void pack_wT(const float* __restrict__ W3,
                                        bf16_t* __restrict__ Wp,
                                        int gt, int gs)
{
  const int nchunk = (1024 * 512) / 8;
  const int ktn = 8;                   // K=512
  for (int c = gt; c < nchunk; c += gs) {
    int lane = c & 63, kk = (c >> 6) & 1, kt = (c >> 7) % ktn;
    int ntile = c / (ktn * 128);
    int jrow = ntile * 16 + (lane & 15);
    int dcol = kt * 64 + kk * 32 + (lane >> 4) * 8;
    bf16_t o[8];
#pragma unroll
    for (int j = 0; j < 8; ++j)
      o[j] = __float2bfloat16(W3[(size_t)(dcol + j) * 1024 + jrow]);
    *(short8*)(Wp + (size_t)c * 8) = *(short8*)o;
  }
}

extern "C" __global__ void init_all(
    const float* __restrict__ x,
    const float* __restrict__ W1, const float* __restrict__ W2,
    const float* __restrict__ W3,
    const float* __restrict__ b1, const float* __restrict__ b3,
    bf16_t* __restrict__ W1b,  bf16_t* __restrict__ W1p,
    bf16_t* __restrict__ W2p,  bf16_t* __restrict__ W3p,
    bf16_t* __restrict__ W3Tp, bf16_t* __restrict__ yb,
    float* __restrict__ c13f,
    float* __restrict__ bS2, float* __restrict__ bS3, float* __restrict__ bS4,
    float* __restrict__ bS5, float* __restrict__ bS6,
    float s2, float s3, float s4, float s5, float s6)
{
  const int gt = blockIdx.x * blockDim.x + threadIdx.x;
  const int gs = gridDim.x * blockDim.x;
  auto cvt4 = [&](const float* in, bf16_t* outp, int n) {
    for (int i = gt * 4; i < n; i += gs * 4) {
      float4 v = *(const float4*)(in + i);
      bf16_t o[4] = {__float2bfloat16(v.x), __float2bfloat16(v.y),
                     __float2bfloat16(v.z), __float2bfloat16(v.w)};
      *(uint64_t*)(outp + i) = *(uint64_t*)o;
    }
  };
  cvt4(W1, W1b, 1024 * 512);           // row-major A for gw13
  cvt4(x, yb, 4096 * 512);
  pack_w(W1, W1p, 1024, 512, gt, gs);
  pack_w(W2, W2p, 1024, 1024, gt, gs);
  pack_w(W3, W3p, 512, 1024, gt, gs);
  pack_wT(W3, W3Tp, gt, gs);
  if (gt < 1024) {
    float c13 = 0.f;
    const float* wr = W1 + (size_t)gt * 512;
    for (int d = 0; d < 512; ++d) c13 += b3[d] * wr[d];
    const float bb = b1[gt];
    c13f[gt] = c13;
    bS2[gt] = bb + s2 * c13;
    bS3[gt] = bb + s3 * c13;
    bS4[gt] = bb + s4 * c13;
    bS5[gt] = bb + s5 * c13;
    bS6[gt] = bb + s6 * c13;
  }
}

// pack bf16 row-major W13 (1024x1024) -> fragment order
extern "C" __global__ void packw13(const bf16_t* __restrict__ W,
                                   bf16_t* __restrict__ Wp)
{
  const int gt = blockIdx.x * blockDim.x + threadIdx.x;
  const int gs = gridDim.x * blockDim.x;
  const int ktn = 16;                  // K=1024
  const int nchunk = (1024 * 1024) / 8;
  for (int c = gt; c < nchunk; c += gs) {
    int lane = c & 63, kk = (c >> 6) & 1, kt = (c >> 7) % ktn;
    int ntile = c / (ktn * 128);
    const bf16_t* src = W + (size_t)(ntile * 16 + (lane & 15)) * 1024
                          + kt * 64 + kk * 32 + (lane >> 4) * 8;
    *(short8*)(Wp + (size_t)c * 8) = *(const short8*)src;
  }
}

// Stotb = bf16(Stot + hsum_63)
extern "C" __global__ void ewfin(const float* __restrict__ Stot,
                                 const bf16_t* __restrict__ hsum,
                                 bf16_t* __restrict__ Stotb, int n)
{
  const int gt = blockIdx.x * blockDim.x + threadIdx.x;
  const int gs = gridDim.x * blockDim.x;
  for (int i = gt * 4; i < n; i += gs * 4) {
    float4 s = *(const float4*)(Stot + i);
    uint64_t hv = *(const uint64_t*)(hsum + i);
    const bf16_t* hp = (const bf16_t*)&hv;
    bf16_t o[4];
    o[0] = __float2bfloat16(s.x + __bfloat162float(hp[0]));
    o[1] = __float2bfloat16(s.y + __bfloat162float(hp[1]));
    o[2] = __float2bfloat16(s.z + __bfloat162float(hp[2]));
    o[3] = __float2bfloat16(s.w + __bfloat162float(hp[3]));
    *(uint64_t*)(Stotb + i) = *(uint64_t*)o;
  }
}

// ---------------------------------------------------------------------------
extern "C" void kernel_launch(void* const* d_in, const int* in_sizes, int n_in,
                              void* d_out, int out_size, void* d_ws, size_t ws_size,
                              hipStream_t stream)
{
  const float* x  = (const float*)d_in[0];
  const float* W1 = (const float*)d_in[1];
  const float* b1 = (const float*)d_in[2];
  const float* W2 = (const float*)d_in[3];
  const float* b2 = (const float*)d_in[4];
  const float* W3 = (const float*)d_in[5];
  const float* b3 = (const float*)d_in[6];

  constexpr int BATCH = 4096, DATA = 512, HID = 1024;

  char* ws = (char*)d_ws;
  size_t off = 0;
  auto alloc = [&](size_t bytes) -> void* {
    off = (off + 255) & ~(size_t)255;
    void* p = ws + off;
    off += bytes;
    return p;
  };
  const size_t nyd = (size_t)BATCH * DATA;
  const size_t nh  = (size_t)BATCH * HID;

  bf16_t* yb   = (bf16_t*)alloc(nyd * 2);
  bf16_t* h1b  = (bf16_t*)alloc(nh * 2);
  bf16_t* h2b  = (bf16_t*)alloc(nh * 2);
  float*  yw1f = (float*)alloc(nh * 4);
  float*  Stot = (float*)alloc(nh * 4);
  bf16_t* Stotb= (bf16_t*)alloc(nh * 2);
  bf16_t* hsumb= (bf16_t*)alloc(nh * 2);
  bf16_t* v1   = (bf16_t*)alloc(nh * 2);
  bf16_t* v2   = (bf16_t*)alloc(nh * 2);
  bf16_t* v3   = (bf16_t*)alloc(nh * 2);
  bf16_t* v4   = (bf16_t*)alloc(nh * 2);
  bf16_t* v5   = (bf16_t*)alloc(nh * 2);
  bf16_t* W1b  = (bf16_t*)alloc((size_t)HID * DATA * 2);
  bf16_t* W1p  = (bf16_t*)alloc((size_t)HID * DATA * 2);
  bf16_t* W2p  = (bf16_t*)alloc((size_t)HID * HID * 2);
  bf16_t* W3p  = (bf16_t*)alloc((size_t)DATA * HID * 2);
  bf16_t* W3Tp = (bf16_t*)alloc((size_t)HID * DATA * 2);
  bf16_t* W13b = (bf16_t*)alloc((size_t)HID * HID * 2);
  bf16_t* W13p = (bf16_t*)alloc((size_t)HID * HID * 2);
  float*  c13f = (float*)alloc(HID * 4);
  float*  bS2  = (float*)alloc(HID * 4);
  float*  bS3  = (float*)alloc(HID * 4);
  float*  bS4  = (float*)alloc(HID * 4);
  float*  bS5  = (float*)alloc(HID * 4);
  float*  bS6  = (float*)alloc(HID * 4);

  const double hh = 1.0 / 64.0;
  const float hA21 = (float)(hh * (1.0/5.0));
  const float hA31 = (float)(hh * (3.0/40.0)),    hA32 = (float)(hh * (9.0/40.0));
  const float hA41 = (float)(hh * (44.0/45.0)),   hA42 = (float)(hh * (-56.0/15.0)),
              hA43 = (float)(hh * (32.0/9.0));
  const float hA51 = (float)(hh * (19372.0/6561.0)),  hA52 = (float)(hh * (-25360.0/2187.0)),
              hA53 = (float)(hh * (64448.0/6561.0)),  hA54 = (float)(hh * (-212.0/729.0));
  const float hA61 = (float)(hh * (9017.0/3168.0)),   hA62 = (float)(hh * (-355.0/33.0)),
              hA63 = (float)(hh * (46732.0/5247.0)),  hA64 = (float)(hh * (49.0/176.0)),
              hA65 = (float)(hh * (-5103.0/18656.0));
  const float hB1 = (float)(hh * (35.0/384.0)),   hB3 = (float)(hh * (500.0/1113.0)),
              hB4 = (float)(hh * (125.0/192.0)),  hB5 = (float)(hh * (-2187.0/6784.0)),
              hB6 = (float)(hh * (11.0/84.0));
  const float s2 = hA21, s3 = hA31 + hA32, s4 = hA41 + hA42 + hA43,
              s5 = hA51 + hA52 + hA53 + hA54,
              s6 = hA61 + hA62 + hA63 + hA64 + hA65;

  init_all<<<2048, 256, 0, stream>>>(x, W1, W2, W3, b1, b3,
                                     W1b, W1p, W2p, W3p, W3Tp, yb,
                                     c13f, bS2, bS3, bS4, bS5, bS6,
                                     s2, s3, s4, s5, s6);

  const dim3 blk(256);
  const int gridN = (HID / 64) * (BATCH / 128);   // 16*32 = 512, lgx=4
  const int gridY = (DATA / 64) * (BATCH / 128);  //  8*32 = 256, lgx=3
  const int gridW = (HID / 64) * (HID / 128);     // 16*8  = 128, lgx=4

  // W13 = W1 @ W3 (A = W1b row-major, B = W3Tp packed), then pack
  gw13<<<gridW, blk, 0, stream>>>(
      W1b, W3Tp, nullptr, W13b, nullptr, nullptr, nullptr, nullptr, nullptr,
      nullptr, nullptr, nullptr, nullptr, 0.f, 0.f, 0.f, 0.f, 0.f, 0,
      HID, HID, DATA, 4);
  packw13<<<2048, 256, 0, stream>>>(W13b, W13p);

  auto G2 = [&](bf16_t* hs, float coef, int hinit) {
    gmid<<<gridN, blk, 0, stream>>>(
        h1b, W2p, b2, h2b, hs, nullptr, nullptr, nullptr, nullptr,
        nullptr, nullptr, nullptr, nullptr,
        0.f, 0.f, 0.f, 0.f, coef, hinit, BATCH, HID, HID, 4);
  };
  auto V = [&](bf16_t* vo, const float* bS, float ccur,
               const bf16_t* q0, float cc0, const bf16_t* q1, float cc1,
               const bf16_t* q2, float cc2, const bf16_t* q3, float cc3) {
    gvst<<<gridN, blk, 0, stream>>>(
        h2b, W13p, bS, h1b, nullptr, vo, yw1f, nullptr, nullptr,
        q0, q1, q2, q3, cc0, cc1, cc2, cc3, ccur, 0, BATCH, HID, HID, 4);
  };

  for (int step = 0; step < 64; ++step) {
    if (step == 0) {
      gyw1<<<gridN, blk, 0, stream>>>(
          yb, W1p, b1, h1b, nullptr, nullptr, yw1f, Stot, nullptr,
          nullptr, nullptr, nullptr, nullptr,
          0.f, 0.f, 0.f, 0.f, 0.f, 0, BATCH, HID, DATA, 4);
    } else {
      gs1v<<<gridN, blk, 0, stream>>>(
          hsumb, W13p, c13f, h1b, nullptr, nullptr, yw1f, Stot, b1,
          hsumb, nullptr, nullptr, nullptr,
          0.f, 0.f, 0.f, 0.f, (float)hh, 0, BATCH, HID, HID, 4);
    }
    G2(hsumb, hB1, 1);
    V(v1, bS2, hA21, nullptr,0,nullptr,0,nullptr,0,nullptr,0);
    G2(nullptr, 0.f, 0);
    V(v2, bS3, hA32, v1,hA31, nullptr,0,nullptr,0,nullptr,0);
    G2(hsumb, hB3, 0);
    V(v3, bS4, hA43, v1,hA41, v2,hA42, nullptr,0,nullptr,0);
    G2(hsumb, hB4, 0);
    V(v4, bS5, hA54, v1,hA51, v2,hA52, v3,hA53, nullptr,0);
    G2(hsumb, hB5, 0);
    V(v5, bS6, hA65, v1,hA61, v2,hA62, v3,hA63, v4,hA64);
    G2(hsumb, hB6, 0);
  }

  ewfin<<<1024, 256, 0, stream>>>(Stot, hsumb, Stotb, (int)nh);
  gfin<<<gridY, blk, 0, stream>>>(
      Stotb, W3p, b3, nullptr, nullptr, nullptr, nullptr, (float*)d_out, x,
      nullptr, nullptr, nullptr, nullptr,
      0.f, 0.f, 0.f, 0.f, 1.0f, 0, BATCH, DATA, HID, 3);
}

// Round 18
// 17503.633 us; speedup vs baseline: 1.3200x; 1.2530x over previous
//
#include <hip/hip_runtime.h>
#include <hip/hip_bf16.h>
#include <stdint.h>
#include <stddef.h>

using bf16_t = __hip_bfloat16;
typedef __attribute__((ext_vector_type(8))) short short8;
typedef __attribute__((ext_vector_type(4))) float f32x4;

__device__ __forceinline__ void gload_lds16(void* lds, const void* g) {
  __builtin_amdgcn_global_load_lds(
      (const __attribute__((address_space(1))) unsigned int*)g,
      (__attribute__((address_space(3))) unsigned int*)lds,
      16, 0, 0);
}

// ---------------------------------------------------------------------------
// r6-proven GEMM core: C[m][n] = sum_k A[m][k]*B[n][k], 64x64 tile, BK=64,
// 4 waves (2x2) of 32x32, 2-buffer LDS ring (32 KB -> 4 blocks/CU), depth-1
// prefetch, 1 barrier/K-step, 16B-chunk XOR swizzle via pre-swizzled source,
// XCD-bijective 1-D grid (nwg % 8 == 0).
// Best-measured configuration (r14 = 17.50 ms). Departures all regressed:
// bigger tiles / lower occupancy (r4,r13,r16,r17), direct-B (r10,r11,r17).
// Epilogue MODEs (algebraic restructure: W13 = W1@W3 composes out G3+G1):
//  0 gmid: h2=relu(acc+bias)->obf;  if(aux) hsum accumulate (bf16 RMW)
//  1 gvst: vout=bf16(acc); u=aux[idx](yw1b) + ccur*acc + sum c_j*p_j[idx]
//          + bias[col] (bias=b1+sigma*c13); obf=bf16(relu(u))
//  2 gyw1: aux[idx]=bf16(acc) (=yW1); obf=bf16(relu(acc+bias))
//  3 gw13: obf=bf16(acc)   (builds W13)
//  4 gyup: z=y_in+acc+ccur*bias[col]; yf_out=z (fp32); obf=bf16(z)
// ---------------------------------------------------------------------------
template<int MODE>
__device__ __forceinline__ void gemm_core(
    const bf16_t* __restrict__ A, const bf16_t* __restrict__ B,
    const float* __restrict__ bias,
    bf16_t* __restrict__ obf,
    bf16_t* __restrict__ aux,          // M0: hsumb  M1: yw1b(rd)  M2: yw1b(wr)
    bf16_t* __restrict__ vout,         // M1: v_{s-1} store
    float* __restrict__ yf_out,        // M4: fp32 y / d_out
    const float* __restrict__ y_in,    // M4
    const bf16_t* __restrict__ kp0, const bf16_t* __restrict__ kp1,
    const bf16_t* __restrict__ kp2, const bf16_t* __restrict__ kp3,
    float c0, float c1, float c2, float c3, float ccur, int hinit,
    int M, int N, int K, int lgx)
{
  __shared__ __align__(16) bf16_t As[2][64 * 64];
  __shared__ __align__(16) bf16_t Bs[2][64 * 64];

  const int t    = threadIdx.x;
  const int lane = t & 63;
  const int wid  = t >> 6;
  const int wm   = wid >> 1;
  const int wn   = wid & 1;

  const int nwg = gridDim.x, bid = blockIdx.x;
  const int swz = (bid & 7) * (nwg >> 3) + (bid >> 3);
  const int gxm = (1 << lgx) - 1;
  const int bx  = swz & gxm;
  const int by  = swz >> lgx;
  const int bn0 = bx * 64, bm0 = by * 64;

  const bf16_t* Ag = A + (size_t)bm0 * K;
  const bf16_t* Bg = B + (size_t)bn0 * K;

  f32x4 acc[2][2] = {};

  auto stage = [&](int b, int kt) {
    const int k0 = kt * 64;
#pragma unroll
    for (int r = 0; r < 2; ++r) {
      int ch  = t + r * 256;
      int row = ch >> 3, s = ch & 7;
      int sl  = s ^ (row & 7);
      gload_lds16(&As[b][ch * 8], Ag + (size_t)row * K + k0 + sl * 8);
    }
#pragma unroll
    for (int r = 0; r < 2; ++r) {
      int ch  = t + r * 256;
      int row = ch >> 3, s = ch & 7;
      int sl  = s ^ (row & 7);
      gload_lds16(&Bs[b][ch * 8], Bg + (size_t)row * K + k0 + sl * 8);
    }
  };

  const int nt = K >> 6;
  stage(0, 0);

  const int ro = lane & 15;
  const int ks = lane >> 4;

  for (int tt = 0; tt < nt; ++tt) {
    const int c = tt & 1;
    asm volatile("s_waitcnt vmcnt(0)" ::: "memory");
    __builtin_amdgcn_s_barrier();
    asm volatile("" ::: "memory");
    if (tt + 1 < nt) stage(c ^ 1, tt + 1);

#pragma unroll
    for (int kk = 0; kk < 2; ++kk) {
      short8 af[2], bfr[2];
      const int slot = kk * 4 + ks;
#pragma unroll
      for (int mi = 0; mi < 2; ++mi) {
        int row = wm * 32 + mi * 16 + ro;
        int ch  = row * 8 + (slot ^ (row & 7));
        af[mi]  = *(const short8*)&As[c][ch * 8];
      }
#pragma unroll
      for (int ni = 0; ni < 2; ++ni) {
        int row = wn * 32 + ni * 16 + ro;
        int ch  = row * 8 + (slot ^ (row & 7));
        bfr[ni] = *(const short8*)&Bs[c][ch * 8];
      }
      __builtin_amdgcn_s_setprio(1);
#pragma unroll
      for (int mi = 0; mi < 2; ++mi)
#pragma unroll
        for (int ni = 0; ni < 2; ++ni)
          acc[mi][ni] = __builtin_amdgcn_mfma_f32_16x16x32_bf16(
              af[mi], bfr[ni], acc[mi][ni], 0, 0, 0);
      __builtin_amdgcn_s_setprio(0);
    }
  }

  // ---- epilogue -----------------------------------------------------------
  const int rb = bm0 + wm * 32;
  const int cb = bn0 + wn * 32;
#pragma unroll
  for (int mi = 0; mi < 2; ++mi) {
#pragma unroll
    for (int ni = 0; ni < 2; ++ni) {
      const int col = cb + ni * 16 + ro;
      const float bv = bias ? bias[col] : 0.f;
#pragma unroll
      for (int r = 0; r < 4; ++r) {
        const int row = rb + mi * 16 + (lane >> 4) * 4 + r;
        const size_t idx = (size_t)row * N + col;
        const float a = acc[mi][ni][r];
        if (MODE == 0) {
          float v = fmaxf(a + bv, 0.f);
          obf[idx] = __float2bfloat16(v);
          if (aux) {
            float hs = ccur * v + (hinit ? 0.f : __bfloat162float(aux[idx]));
            aux[idx] = __float2bfloat16(hs);
          }
        } else if (MODE == 1) {
          vout[idx] = __float2bfloat16(a);
          float u = __bfloat162float(aux[idx]) + ccur * a + bv;
          if (kp0) u += c0 * __bfloat162float(kp0[idx]);
          if (kp1) u += c1 * __bfloat162float(kp1[idx]);
          if (kp2) u += c2 * __bfloat162float(kp2[idx]);
          if (kp3) u += c3 * __bfloat162float(kp3[idx]);
          obf[idx] = __float2bfloat16(fmaxf(u, 0.f));
        } else if (MODE == 2) {
          aux[idx] = __float2bfloat16(a);
          obf[idx] = __float2bfloat16(fmaxf(a + bv, 0.f));
        } else if (MODE == 3) {
          obf[idx] = __float2bfloat16(a);
        } else {  // MODE 4
          float z = y_in[idx] + a + ccur * bv;
          yf_out[idx] = z;
          obf[idx] = __float2bfloat16(z);
        }
      }
    }
  }
}

#define GARGS                                                               \
    const bf16_t* A, const bf16_t* B, const float* bias, bf16_t* obf,       \
    bf16_t* aux, bf16_t* vout, float* yf_out, const float* y_in,            \
    const bf16_t* p0, const bf16_t* p1, const bf16_t* p2, const bf16_t* p3, \
    float c0, float c1, float c2, float c3, float ccur, int hinit,          \
    int M, int N, int K, int lgx
#define GPASS A,B,bias,obf,aux,vout,yf_out,y_in,p0,p1,p2,p3,c0,c1,c2,c3,ccur,hinit,M,N,K,lgx

extern "C" __global__ void __launch_bounds__(256, 4) gmid(GARGS) { gemm_core<0>(GPASS); }
extern "C" __global__ void __launch_bounds__(256, 4) gvst(GARGS) { gemm_core<1>(GPASS); }
extern "C" __global__ void __launch_bounds__(256, 4) gyw1(GARGS) { gemm_core<2>(GPASS); }
extern "C" __global__ void __launch_bounds__(256, 4) gw13(GARGS) { gemm_core<3>(GPASS); }
extern "C" __global__ void __launch_bounds__(256, 4) gyup(GARGS) { gemm_core<4>(GPASS); }

// ---------------------------------------------------------------------------
// init: W1/W2/W3 -> bf16; W3T (transposed bf16, for W13 build); y=x; yb;
// c13[c] = sum_d b3[d]*W1[c][d]; biasS_s = b1 + sigma_s*c13 (s=2..6)
// ---------------------------------------------------------------------------
extern "C" __global__ void init_all(
    const float* __restrict__ x,
    const float* __restrict__ W1, const float* __restrict__ W2,
    const float* __restrict__ W3,
    const float* __restrict__ b1, const float* __restrict__ b3,
    bf16_t* __restrict__ W1b, bf16_t* __restrict__ W2b,
    bf16_t* __restrict__ W3b, bf16_t* __restrict__ W3Tb,
    float* __restrict__ y, bf16_t* __restrict__ yb,
    float* __restrict__ bS2, float* __restrict__ bS3, float* __restrict__ bS4,
    float* __restrict__ bS5, float* __restrict__ bS6,
    float s2, float s3, float s4, float s5, float s6)
{
  const int gt = blockIdx.x * blockDim.x + threadIdx.x;
  const int gs = gridDim.x * blockDim.x;
  auto cvt4 = [&](const float* in, bf16_t* outp, int n) {
    for (int i = gt * 4; i < n; i += gs * 4) {
      float4 v = *(const float4*)(in + i);
      bf16_t o[4] = {__float2bfloat16(v.x), __float2bfloat16(v.y),
                     __float2bfloat16(v.z), __float2bfloat16(v.w)};
      *(uint64_t*)(outp + i) = *(uint64_t*)o;
    }
  };
  cvt4(W1, W1b, 1024 * 512);
  cvt4(W2, W2b, 1024 * 1024);
  cvt4(W3, W3b, 512 * 1024);
  for (int i = gt; i < 512 * 1024; i += gs) {      // W3T[j][d] = W3[d][j]
    int d = i >> 10, j = i & 1023;
    W3Tb[(size_t)j * 512 + d] = __float2bfloat16(W3[i]);
  }
  for (int i = gt * 4; i < 4096 * 512; i += gs * 4) {
    float4 v = *(const float4*)(x + i);
    *(float4*)(y + i) = v;
    bf16_t o[4] = {__float2bfloat16(v.x), __float2bfloat16(v.y),
                   __float2bfloat16(v.z), __float2bfloat16(v.w)};
    *(uint64_t*)(yb + i) = *(uint64_t*)o;
  }
  if (gt < 1024) {                                  // c13 + stage biases
    float c13 = 0.f;
    const float* wr = W1 + (size_t)gt * 512;
    for (int d = 0; d < 512; ++d) c13 += b3[d] * wr[d];
    const float bb = b1[gt];
    bS2[gt] = bb + s2 * c13;
    bS3[gt] = bb + s3 * c13;
    bS4[gt] = bb + s4 * c13;
    bS5[gt] = bb + s5 * c13;
    bS6[gt] = bb + s6 * c13;
  }
}

// ---------------------------------------------------------------------------
extern "C" void kernel_launch(void* const* d_in, const int* in_sizes, int n_in,
                              void* d_out, int out_size, void* d_ws, size_t ws_size,
                              hipStream_t stream)
{
  const float* x  = (const float*)d_in[0];
  const float* W1 = (const float*)d_in[1];
  const float* b1 = (const float*)d_in[2];
  const float* W2 = (const float*)d_in[3];
  const float* b2 = (const float*)d_in[4];
  const float* W3 = (const float*)d_in[5];
  const float* b3 = (const float*)d_in[6];

  constexpr int BATCH = 4096, DATA = 512, HID = 1024;

  char* ws = (char*)d_ws;
  size_t off = 0;
  auto alloc = [&](size_t bytes) -> void* {
    off = (off + 255) & ~(size_t)255;
    void* p = ws + off;
    off += bytes;
    return p;
  };
  const size_t nyd = (size_t)BATCH * DATA;
  const size_t nh  = (size_t)BATCH * HID;

  float*  y    = (float*)alloc(nyd * 4);
  bf16_t* yb   = (bf16_t*)alloc(nyd * 2);
  bf16_t* h1b  = (bf16_t*)alloc(nh * 2);
  bf16_t* h2b  = (bf16_t*)alloc(nh * 2);
  bf16_t* yw1b = (bf16_t*)alloc(nh * 2);
  bf16_t* hsumb= (bf16_t*)alloc(nh * 2);
  bf16_t* v1   = (bf16_t*)alloc(nh * 2);
  bf16_t* v2   = (bf16_t*)alloc(nh * 2);
  bf16_t* v3   = (bf16_t*)alloc(nh * 2);
  bf16_t* v4   = (bf16_t*)alloc(nh * 2);
  bf16_t* v5   = (bf16_t*)alloc(nh * 2);
  bf16_t* W1b  = (bf16_t*)alloc((size_t)HID * DATA * 2);
  bf16_t* W2b  = (bf16_t*)alloc((size_t)HID * HID * 2);
  bf16_t* W3b  = (bf16_t*)alloc((size_t)DATA * HID * 2);
  bf16_t* W3Tb = (bf16_t*)alloc((size_t)HID * DATA * 2);
  bf16_t* W13b = (bf16_t*)alloc((size_t)HID * HID * 2);
  float*  bS2  = (float*)alloc(HID * 4);
  float*  bS3  = (float*)alloc(HID * 4);
  float*  bS4  = (float*)alloc(HID * 4);
  float*  bS5  = (float*)alloc(HID * 4);
  float*  bS6  = (float*)alloc(HID * 4);

  const double hh = 1.0 / 64.0;
  const float hA21 = (float)(hh * (1.0/5.0));
  const float hA31 = (float)(hh * (3.0/40.0)),    hA32 = (float)(hh * (9.0/40.0));
  const float hA41 = (float)(hh * (44.0/45.0)),   hA42 = (float)(hh * (-56.0/15.0)),
              hA43 = (float)(hh * (32.0/9.0));
  const float hA51 = (float)(hh * (19372.0/6561.0)),  hA52 = (float)(hh * (-25360.0/2187.0)),
              hA53 = (float)(hh * (64448.0/6561.0)),  hA54 = (float)(hh * (-212.0/729.0));
  const float hA61 = (float)(hh * (9017.0/3168.0)),   hA62 = (float)(hh * (-355.0/33.0)),
              hA63 = (float)(hh * (46732.0/5247.0)),  hA64 = (float)(hh * (49.0/176.0)),
              hA65 = (float)(hh * (-5103.0/18656.0));
  const float hB1 = (float)(hh * (35.0/384.0)),   hB3 = (float)(hh * (500.0/1113.0)),
              hB4 = (float)(hh * (125.0/192.0)),  hB5 = (float)(hh * (-2187.0/6784.0)),
              hB6 = (float)(hh * (11.0/84.0));
  const float s2 = hA21, s3 = hA31 + hA32, s4 = hA41 + hA42 + hA43,
              s5 = hA51 + hA52 + hA53 + hA54,
              s6 = hA61 + hA62 + hA63 + hA64 + hA65;

  init_all<<<2048, 256, 0, stream>>>(x, W1, W2, W3, b1, b3,
                                     W1b, W2b, W3b, W3Tb, y, yb,
                                     bS2, bS3, bS4, bS5, bS6,
                                     s2, s3, s4, s5, s6);

  const dim3 blk(256);
  const int gridN = (HID / 64) * (BATCH / 64);    // 1024, lgx=4
  const int gridY = (DATA / 64) * (BATCH / 64);   // 512,  lgx=3
  const int gridW = (HID / 64) * (HID / 64);      // 256,  lgx=4

  // W13 = W1 @ W3  (C[i][j] = sum_d W1b[i][d] * W3Tb[j][d])
  gw13<<<gridW, blk, 0, stream>>>(
      W1b, W3Tb, nullptr, W13b, nullptr, nullptr, nullptr, nullptr,
      nullptr, nullptr, nullptr, nullptr, 0.f, 0.f, 0.f, 0.f, 0.f, 0,
      HID, HID, DATA, 4);

  auto G2 = [&](bf16_t* hs, float coef, int hinit) {
    gmid<<<gridN, blk, 0, stream>>>(
        h1b, W2b, b2, h2b, hs, nullptr, nullptr, nullptr,
        nullptr, nullptr, nullptr, nullptr,
        0.f, 0.f, 0.f, 0.f, coef, hinit, BATCH, HID, HID, 4);
  };
  auto V = [&](bf16_t* vo, const float* bS, float ccur,
               const bf16_t* q0, float cc0, const bf16_t* q1, float cc1,
               const bf16_t* q2, float cc2, const bf16_t* q3, float cc3) {
    gvst<<<gridN, blk, 0, stream>>>(
        h2b, W13b, bS, h1b, yw1b, vo, nullptr, nullptr,
        q0, q1, q2, q3, cc0, cc1, cc2, cc3, ccur, 0, BATCH, HID, HID, 4);
  };

  for (int step = 0; step < 64; ++step) {
    // stage 1: yW1 GEMM (K=512), h1_1 = relu(yW1 + b1), store yw1b
    gyw1<<<gridN, blk, 0, stream>>>(
        yb, W1b, b1, h1b, yw1b, nullptr, nullptr, nullptr,
        nullptr, nullptr, nullptr, nullptr,
        0.f, 0.f, 0.f, 0.f, 0.f, 0, BATCH, HID, DATA, 4);
    G2(hsumb, hB1, 1);                                   // h2_1, hsum init
    // stages 2..6: v_{s-1} GEMM + fused h1_s epilogue, then G2
    V(v1, bS2, hA21, nullptr,0,nullptr,0,nullptr,0,nullptr,0);
    G2(nullptr, 0.f, 0);                                 // h2_2 (B2 = 0)
    V(v2, bS3, hA32, v1,hA31, nullptr,0,nullptr,0,nullptr,0);
    G2(hsumb, hB3, 0);                                   // h2_3
    V(v3, bS4, hA43, v1,hA41, v2,hA42, nullptr,0,nullptr,0);
    G2(hsumb, hB4, 0);                                   // h2_4
    V(v4, bS5, hA54, v1,hA51, v2,hA52, v3,hA53, nullptr,0);
    G2(hsumb, hB5, 0);                                   // h2_5
    V(v5, bS6, hA65, v1,hA61, v2,hA62, v3,hA63, v4,hA64);
    G2(hsumb, hB6, 0);                                   // h2_6, hsum final
    // y_{n+1} = y + hsum@W3^T + h*b3   (sum B_j = 1)
    float* yf = (step == 63) ? (float*)d_out : y;
    gyup<<<gridY, blk, 0, stream>>>(
        hsumb, W3b, b3, yb, nullptr, nullptr, yf, y,
        nullptr, nullptr, nullptr, nullptr,
        0.f, 0.f, 0.f, 0.f, (float)hh, 0, BATCH, DATA, HID, 3);
  }
}